// Round 6
// baseline (261.638 us; speedup 1.0000x reference)
//
#include <hip/hip_runtime.h>

#define N_SUP 4096
#define N_QRY 8192
#define IN_DIM 784
#define EMB 512
#define NCLS 64
#define M_TOT (N_SUP + N_QRY)
#define NCHUNK 25   // ceil(784/32)

typedef _Float16 f16;
typedef _Float16 f16x8 __attribute__((ext_vector_type(8)));
typedef float f32x4 __attribute__((ext_vector_type(4)));

// load 8 consecutive fp32 and convert to f16x8
static __device__ __forceinline__ f16x8 cvt8(const float* p) {
    float4 a = *(const float4*)p;
    float4 b = *(const float4*)(p + 4);
    f16x8 v;
    v[0] = (f16)a.x; v[1] = (f16)a.y; v[2] = (f16)a.z; v[3] = (f16)a.w;
    v[4] = (f16)b.x; v[5] = (f16)b.y; v[6] = (f16)b.z; v[7] = (f16)b.w;
    return v;
}

// ---- prep: W (784x512 fp32) -> Wb in MFMA B-frag order:
// Wb[((chunk*32 + nbg)*64 + lane)*8 + j] = f16(W[k][n]),
//   n = nbg*16 + (lane&15), k = chunk*32 + (lane>>4)*8 + j  (0 if k>=784)
__global__ __launch_bounds__(256) void prep_wb(const float* __restrict__ W,
                                               f16* __restrict__ Wb) {
    int g = blockIdx.x * 256 + threadIdx.x;          // 51200 frag-lanes
    if (g >= NCHUNK * 32 * 64) return;
    int chunk = g >> 11;                             // /(32*64)
    int rem = g & 2047;
    int nbg = rem >> 6, lane = rem & 63;
    int n = nbg * 16 + (lane & 15);
    int kbase = chunk * 32 + (lane >> 4) * 8;
    f16x8 v;
#pragma unroll
    for (int j = 0; j < 8; ++j) {
        int k = kbase + j;
        v[j] = (k < IN_DIM) ? (f16)W[(size_t)k * EMB + n] : (f16)0.f;
    }
    *(f16x8*)(Wb + (size_t)g * 8) = v;
}

// ---- prep: one-hot labels -> argmax -> Lcs[c][s] (64 x 4096 f16) ----
__global__ __launch_bounds__(256) void prep_labels(const float* __restrict__ lab,
                                                   f16* __restrict__ Lcs) {
    int s = blockIdx.x * 256 + threadIdx.x;
    if (s >= N_SUP) return;
    int best = 0; float bv = -1e30f;
    for (int c = 0; c < NCLS; ++c) {
        float v = lab[s * NCLS + c];
        if (v > bv) { bv = v; best = c; }
    }
#pragma unroll
    for (int c = 0; c < NCLS; ++c)
        Lcs[(size_t)c * N_SUP + s] = (c == best) ? (f16)1.f : (f16)0.f;
}

// ---- encode: full-N tiles. 64 rows x 512 cols per block, grid 192.
// X staged in LDS (read once from HBM); W B-frags direct from global Wb (L2).
// Wave w: rows (w&1)*32 (2 m-frags), cols (w>>1)*256 (16 nb).
__global__ __launch_bounds__(256) void encode(
    const float* __restrict__ sup, const float* __restrict__ qry,
    const f16* __restrict__ Wb, const float* __restrict__ bias,
    f16* __restrict__ E, float* __restrict__ norms)
{
    __shared__ __align__(16) f16 Xs[64][40];
    __shared__ float normS[64];
    const int tid = threadIdx.x;
    const int w = tid >> 6, lane = tid & 63;
    const int q = lane >> 4, c16 = lane & 15;
    const int m0 = blockIdx.x * 64;
    const int rbase = (w & 1) * 32;          // wave's row offset in tile
    const int cbase = (w >> 1) * 256;        // wave's col offset
    const int nbg0 = (w >> 1) * 16;          // global nb offset

    f32x4 acc[2][16];
#pragma unroll
    for (int h = 0; h < 2; ++h)
#pragma unroll
        for (int nb = 0; nb < 16; ++nb) acc[h][nb] = (f32x4){0.f, 0.f, 0.f, 0.f};

    if (tid < 64) normS[tid] = 0.f;

    const int sr = tid >> 2;            // staging row 0..63
    const int sq = tid & 3;             // k-seg 0..3 (x8)
    const float* xrow;
    {
        int gr = m0 + sr;
        xrow = (gr < N_SUP) ? sup + (size_t)gr * IN_DIM
                            : qry + (size_t)(gr - N_SUP) * IN_DIM;
    }

    // prologue: load chunk 0 (all k valid)
    f16x8 xg = cvt8(xrow + sq * 8);

    for (int c = 0; c < NCHUNK; ++c) {
        __syncthreads();
        *(f16x8*)&Xs[sr][sq * 8] = xg;
        __syncthreads();
        // prefetch next chunk's X
        if (c + 1 < NCHUNK) {
            int k = (c + 1) * 32 + sq * 8;
            if (k + 8 <= IN_DIM) xg = cvt8(xrow + k);
            else xg = (f16x8){0,0,0,0,0,0,0,0};
        }
        f16x8 a0 = *(const f16x8*)&Xs[rbase + c16][q * 8];
        f16x8 a1 = *(const f16x8*)&Xs[rbase + 16 + c16][q * 8];
        const f16* wb = Wb + ((size_t)(c * 32 + nbg0) * 64 + lane) * 8;
#pragma unroll
        for (int nb = 0; nb < 16; ++nb) {
            f16x8 b = *(const f16x8*)(wb + (size_t)nb * 512);
            acc[0][nb] = __builtin_amdgcn_mfma_f32_16x16x32_f16(a0, b, acc[0][nb], 0, 0, 0);
            acc[1][nb] = __builtin_amdgcn_mfma_f32_16x16x32_f16(a1, b, acc[1][nb], 0, 0, 0);
        }
    }

    // epilogue: bias, E store, norms via LDS reduction
    float nrm[2][4] = {};
#pragma unroll
    for (int nb = 0; nb < 16; ++nb) {
        int col = cbase + nb * 16 + c16;
        float bv = bias[col];
#pragma unroll
        for (int h = 0; h < 2; ++h)
#pragma unroll
            for (int r = 0; r < 4; ++r) {
                int rowl = rbase + h * 16 + q * 4 + r;
                float v = acc[h][nb][r] + bv;
                E[(size_t)(m0 + rowl) * EMB + col] = (f16)v;
                nrm[h][r] += v * v;
            }
    }
#pragma unroll
    for (int h = 0; h < 2; ++h)
#pragma unroll
        for (int r = 0; r < 4; ++r) {
            float v = nrm[h][r];
            v += __shfl_xor(v, 1); v += __shfl_xor(v, 2);
            v += __shfl_xor(v, 4); v += __shfl_xor(v, 8);
            if (c16 == 0) atomicAdd(&normS[rbase + h * 16 + q * 4 + r], v);
        }
    __syncthreads();
    if (tid < 64) norms[m0 + tid] = normS[tid];
}

// ---- anchor: m[q] = d(query q, support 0) — global softmax shift ----
__global__ __launch_bounds__(256) void anchor(const f16* __restrict__ E,
                                              const float* __restrict__ norms,
                                              float* __restrict__ manc) {
    __shared__ float s0e[EMB];
    const int tid = threadIdx.x;
    s0e[tid] = (float)E[tid];
    s0e[tid + 256] = (float)E[tid + 256];
    __syncthreads();
    const int qrow = blockIdx.x * 256 + tid;
    const f16* qp = E + (size_t)(N_SUP + qrow) * EMB;
    float dot = 0.f;
    for (int k = 0; k < EMB; k += 8) {
        f16x8 v = *(const f16x8*)(qp + k);
#pragma unroll
        for (int j = 0; j < 8; ++j) dot += (float)v[j] * s0e[k + j];
    }
    float d2 = fmaxf(norms[N_SUP + qrow] + norms[0] - 2.f * dot, 0.f);
    manc[qrow] = sqrtf(d2);
}

// ---- attn: QK-dist -> p=exp(m-d) -> P*onehot(L) via MFMA. (unchanged R5) ----
__global__ __launch_bounds__(256, 3) void attn(
    const f16* __restrict__ E, const float* __restrict__ norms,
    const float* __restrict__ manc, const f16* __restrict__ Lcs,
    float* __restrict__ Num)
{
    __shared__ __align__(16) f16 Ss[2][64][136];
    __shared__ __align__(16) f16 Pt[4][16][72];   // per-wave P transpose buffer
    const int tid = threadIdx.x;
    const int w = tid >> 6, lane = tid & 63;
    const int q = lane >> 4, c16 = lane & 15;
    const int qt = blockIdx.x, ss = blockIdx.y;

    // resident Q fragments (A-layout m=c16): 16 x f16x8 = 64 VGPRs
    f16x8 qf[16];
    const f16* qb = E + (size_t)(N_SUP + qt * 64 + w * 16 + c16) * EMB + q * 8;
#pragma unroll
    for (int ks = 0; ks < 16; ++ks) qf[ks] = *(const f16x8*)(qb + ks * 32);
    float q2[4], mrow[4];
#pragma unroll
    for (int r = 0; r < 4; ++r) {
        q2[r]   = norms[N_SUP + qt * 64 + w * 16 + q * 4 + r];
        mrow[r] = manc[qt * 64 + w * 16 + q * 4 + r];
    }

    f32x4 accPL[4];
#pragma unroll
    for (int nb = 0; nb < 4; ++nb) accPL[nb] = (f32x4){0.f, 0.f, 0.f, 0.f};

    const int sr = tid >> 2, koff0 = (tid & 3) * 8;
    const f16* sbase = E + (size_t)(ss * 512 + sr) * EMB;

    // prologue: stage chunk 0 (it=0, kc=0)
    f16x8 g[4];
#pragma unroll
    for (int i = 0; i < 4; ++i) g[i] = *(const f16x8*)(sbase + koff0 + i * 32);
#pragma unroll
    for (int i = 0; i < 4; ++i) *(f16x8*)&Ss[0][sr][koff0 + i * 32] = g[i];
    __syncthreads();

    for (int it = 0; it < 8; ++it) {
        f32x4 accQK[4];
#pragma unroll
        for (int nb = 0; nb < 4; ++nb) accQK[nb] = (f32x4){0.f, 0.f, 0.f, 0.f};
#pragma unroll
        for (int kc = 0; kc < 4; ++kc) {
            const int idx = it * 4 + kc;
            const int cur = idx & 1;
            if (idx + 1 < 32) {   // prefetch next chunk: overlap with compute below
                const int nit = (idx + 1) >> 2, nkc = (idx + 1) & 3;
                const f16* src = sbase + (size_t)(nit * 64) * EMB + nkc * 128 + koff0;
#pragma unroll
                for (int i = 0; i < 4; ++i) g[i] = *(const f16x8*)(src + i * 32);
            }
#pragma unroll
            for (int ksl = 0; ksl < 4; ++ksl) {
#pragma unroll
                for (int nb = 0; nb < 4; ++nb) {
                    f16x8 b = *(const f16x8*)&Ss[cur][nb * 16 + c16][ksl * 32 + q * 8];
                    accQK[nb] = __builtin_amdgcn_mfma_f32_16x16x32_f16(qf[kc * 4 + ksl], b, accQK[nb], 0, 0, 0);
                }
            }
            if (idx + 1 < 32) {
#pragma unroll
                for (int i = 0; i < 4; ++i) *(f16x8*)&Ss[cur ^ 1][sr][koff0 + i * 32] = g[i];
            }
            __syncthreads();
        }
        // epilogue: p = exp(m - d), wave-private LDS transpose, P*L MFMA
        const int s0g = ss * 512 + it * 64;
#pragma unroll
        for (int nb = 0; nb < 4; ++nb) {
            const int col = s0g + nb * 16 + c16;
            const float s2 = norms[col];
#pragma unroll
            for (int r = 0; r < 4; ++r) {
                float d2 = fmaxf(q2[r] + s2 - 2.f * accQK[nb][r], 0.f);
                float p = __expf(mrow[r] - sqrtf(d2));
                p = fminf(p, 60000.f);     // f16-overflow guard (≥10σ tail only)
                Pt[w][q * 4 + r][nb * 16 + c16] = (f16)p;
            }
        }
#pragma unroll
        for (int kc2 = 0; kc2 < 2; ++kc2) {
            f16x8 af = *(const f16x8*)&Pt[w][c16][kc2 * 32 + q * 8];
#pragma unroll
            for (int nbc = 0; nbc < 4; ++nbc) {
                f16x8 bl = *(const f16x8*)(Lcs + (size_t)(nbc * 16 + c16) * N_SUP + s0g + kc2 * 32 + q * 8);
                accPL[nbc] = __builtin_amdgcn_mfma_f32_16x16x32_f16(af, bl, accPL[nbc], 0, 0, 0);
            }
        }
    }
    // flush Num partials (8 ss-chunks contend via global f32 atomics)
#pragma unroll
    for (int nbc = 0; nbc < 4; ++nbc)
#pragma unroll
        for (int r = 0; r < 4; ++r)
            atomicAdd(&Num[(size_t)(qt * 64 + w * 16 + q * 4 + r) * NCLS + nbc * 16 + c16],
                      accPL[nbc][r]);
}

// ---- finalize: out[q][c] = Num[q][c] / rowsum(Num[q]) ----
__global__ __launch_bounds__(256) void finalize(const float* __restrict__ Num,
                                                float* __restrict__ out) {
    const int tid = threadIdx.x;
    const int w = tid >> 6, lane = tid & 63;
    const int qrow = blockIdx.x * 4 + w;
    float v = Num[(size_t)qrow * NCLS + lane];
    float s = v;
    s += __shfl_xor(s, 1);  s += __shfl_xor(s, 2);  s += __shfl_xor(s, 4);
    s += __shfl_xor(s, 8);  s += __shfl_xor(s, 16); s += __shfl_xor(s, 32);
    out[(size_t)qrow * NCLS + lane] = v / s;
}

extern "C" void kernel_launch(void* const* d_in, const int* in_sizes, int n_in,
                              void* d_out, int out_size, void* d_ws, size_t ws_size,
                              hipStream_t stream) {
    (void)in_sizes; (void)n_in; (void)out_size; (void)ws_size;
    const float* sup  = (const float*)d_in[0];
    const float* qry  = (const float*)d_in[1];
    const float* lab  = (const float*)d_in[2];
    const float* Wenc = (const float*)d_in[3];
    const float* benc = (const float*)d_in[4];
    float* out = (float*)d_out;

    char* ws = (char*)d_ws;
    size_t off = 0;
    f16* Wb = (f16*)(ws + off);        off += (size_t)NCHUNK * 32 * 64 * 8 * 2; // 819200
    f16* E  = (f16*)(ws + off);        off += (size_t)M_TOT * EMB * 2;          // 12582912
    float* norms = (float*)(ws + off); off += (size_t)M_TOT * 4;                // 49152
    f16* Lcs = (f16*)(ws + off);       off += (size_t)NCLS * N_SUP * 2;         // 524288
    float* manc = (float*)(ws + off);  off += (size_t)N_QRY * 4;                // 32768
    float* Num = (float*)(ws + off);   off += (size_t)N_QRY * NCLS * 4;         // 2097152

    hipMemsetAsync(Num, 0, (size_t)N_QRY * NCLS * 4, stream);

    prep_wb<<<(NCHUNK * 32 * 64 + 255) / 256, 256, 0, stream>>>(Wenc, Wb);
    prep_labels<<<N_SUP / 256, 256, 0, stream>>>(lab, Lcs);
    encode<<<M_TOT / 64, 256, 0, stream>>>(sup, qry, Wb, benc, E, norms);
    anchor<<<N_QRY / 256, 256, 0, stream>>>(E, norms, manc);
    attn<<<dim3(N_QRY / 64, 8), 256, 0, stream>>>(E, norms, manc, Lcs, Num);
    finalize<<<N_QRY / 4, 256, 0, stream>>>(Num, out);
}

// Round 7
// 255.727 us; speedup vs baseline: 1.0231x; 1.0231x over previous
//
#include <hip/hip_runtime.h>

#define N_SUP 4096
#define N_QRY 8192
#define IN_DIM 784
#define EMB 512
#define NCLS 64
#define M_TOT (N_SUP + N_QRY)
#define NCHUNK 25   // ceil(784/32)

typedef _Float16 f16;
typedef _Float16 f16x8 __attribute__((ext_vector_type(8)));
typedef float f32x4 __attribute__((ext_vector_type(4)));

// load 8 consecutive fp32 and convert to f16x8
static __device__ __forceinline__ f16x8 cvt8(const float* p) {
    float4 a = *(const float4*)p;
    float4 b = *(const float4*)(p + 4);
    f16x8 v;
    v[0] = (f16)a.x; v[1] = (f16)a.y; v[2] = (f16)a.z; v[3] = (f16)a.w;
    v[4] = (f16)b.x; v[5] = (f16)b.y; v[6] = (f16)b.z; v[7] = (f16)b.w;
    return v;
}

// ---- prep: W (784x512 fp32) -> Wb in MFMA B-frag order ----
__global__ __launch_bounds__(256) void prep_wb(const float* __restrict__ W,
                                               f16* __restrict__ Wb) {
    int g = blockIdx.x * 256 + threadIdx.x;          // 51200 frag-lanes
    if (g >= NCHUNK * 32 * 64) return;
    int chunk = g >> 11;
    int rem = g & 2047;
    int nbg = rem >> 6, lane = rem & 63;
    int n = nbg * 16 + (lane & 15);
    int kbase = chunk * 32 + (lane >> 4) * 8;
    f16x8 v;
#pragma unroll
    for (int j = 0; j < 8; ++j) {
        int k = kbase + j;
        v[j] = (k < IN_DIM) ? (f16)W[(size_t)k * EMB + n] : (f16)0.f;
    }
    *(f16x8*)(Wb + (size_t)g * 8) = v;
}

// ---- prep: one-hot labels (4096x64 fp32) -> argmax index ----
__global__ __launch_bounds__(256) void prep_lbl(const float* __restrict__ lab,
                                                int* __restrict__ lbl) {
    int s = blockIdx.x * 256 + threadIdx.x;
    if (s >= N_SUP) return;
    int best = 0; float bv = -1e30f;
    for (int c = 0; c < NCLS; ++c) {
        float v = lab[s * NCLS + c];
        if (v > bv) { bv = v; best = c; }
    }
    lbl[s] = best;
}

// ---- prep: Lcs[c][s] one-hot transpose (coalesced reads+writes) ----
__global__ __launch_bounds__(256) void prep_L(const int* __restrict__ lbl,
                                              f16* __restrict__ Lcs) {
    int idx = blockIdx.x * 256 + threadIdx.x;
    if (idx >= NCLS * N_SUP) return;
    int c = idx >> 12, s = idx & (N_SUP - 1);
    Lcs[idx] = (lbl[s] == c) ? (f16)1.f : (f16)0.f;
}

// ---- encode: full-N tiles. 64 rows x 512 cols per block, grid 192. ----
__global__ __launch_bounds__(256) void encode(
    const float* __restrict__ sup, const float* __restrict__ qry,
    const f16* __restrict__ Wb, const float* __restrict__ bias,
    f16* __restrict__ E, float* __restrict__ norms)
{
    __shared__ __align__(16) f16 Xs[64][40];
    __shared__ float normS[64];
    const int tid = threadIdx.x;
    const int w = tid >> 6, lane = tid & 63;
    const int q = lane >> 4, c16 = lane & 15;
    const int m0 = blockIdx.x * 64;
    const int rbase = (w & 1) * 32;
    const int cbase = (w >> 1) * 256;
    const int nbg0 = (w >> 1) * 16;

    f32x4 acc[2][16];
#pragma unroll
    for (int h = 0; h < 2; ++h)
#pragma unroll
        for (int nb = 0; nb < 16; ++nb) acc[h][nb] = (f32x4){0.f, 0.f, 0.f, 0.f};

    if (tid < 64) normS[tid] = 0.f;

    const int sr = tid >> 2;
    const int sq = tid & 3;
    const float* xrow;
    {
        int gr = m0 + sr;
        xrow = (gr < N_SUP) ? sup + (size_t)gr * IN_DIM
                            : qry + (size_t)(gr - N_SUP) * IN_DIM;
    }

    f16x8 xg = cvt8(xrow + sq * 8);

    for (int c = 0; c < NCHUNK; ++c) {
        __syncthreads();
        *(f16x8*)&Xs[sr][sq * 8] = xg;
        __syncthreads();
        if (c + 1 < NCHUNK) {
            int k = (c + 1) * 32 + sq * 8;
            if (k + 8 <= IN_DIM) xg = cvt8(xrow + k);
            else xg = (f16x8){0,0,0,0,0,0,0,0};
        }
        f16x8 a0 = *(const f16x8*)&Xs[rbase + c16][q * 8];
        f16x8 a1 = *(const f16x8*)&Xs[rbase + 16 + c16][q * 8];
        const f16* wb = Wb + ((size_t)(c * 32 + nbg0) * 64 + lane) * 8;
#pragma unroll
        for (int nb = 0; nb < 16; ++nb) {
            f16x8 b = *(const f16x8*)(wb + (size_t)nb * 512);
            acc[0][nb] = __builtin_amdgcn_mfma_f32_16x16x32_f16(a0, b, acc[0][nb], 0, 0, 0);
            acc[1][nb] = __builtin_amdgcn_mfma_f32_16x16x32_f16(a1, b, acc[1][nb], 0, 0, 0);
        }
    }

    float nrm[2][4] = {};
#pragma unroll
    for (int nb = 0; nb < 16; ++nb) {
        int col = cbase + nb * 16 + c16;
        float bv = bias[col];
#pragma unroll
        for (int h = 0; h < 2; ++h)
#pragma unroll
            for (int r = 0; r < 4; ++r) {
                int rowl = rbase + h * 16 + q * 4 + r;
                float v = acc[h][nb][r] + bv;
                E[(size_t)(m0 + rowl) * EMB + col] = (f16)v;
                nrm[h][r] += v * v;
            }
    }
#pragma unroll
    for (int h = 0; h < 2; ++h)
#pragma unroll
        for (int r = 0; r < 4; ++r) {
            float v = nrm[h][r];
            v += __shfl_xor(v, 1); v += __shfl_xor(v, 2);
            v += __shfl_xor(v, 4); v += __shfl_xor(v, 8);
            if (c16 == 0) atomicAdd(&normS[rbase + h * 16 + q * 4 + r], v);
        }
    __syncthreads();
    if (tid < 64) norms[m0 + tid] = normS[tid];
}

// ---- anchor: m[q] = d(query q, support 0) — global softmax shift ----
__global__ __launch_bounds__(256) void anchor(const f16* __restrict__ E,
                                              const float* __restrict__ norms,
                                              float* __restrict__ manc) {
    __shared__ float s0e[EMB];
    const int tid = threadIdx.x;
    s0e[tid] = (float)E[tid];
    s0e[tid + 256] = (float)E[tid + 256];
    __syncthreads();
    const int qrow = blockIdx.x * 256 + tid;
    const f16* qp = E + (size_t)(N_SUP + qrow) * EMB;
    float dot = 0.f;
    for (int k = 0; k < EMB; k += 8) {
        f16x8 v = *(const f16x8*)(qp + k);
#pragma unroll
        for (int j = 0; j < 8; ++j) dot += (float)v[j] * s0e[k + j];
    }
    float d2 = fmaxf(norms[N_SUP + qrow] + norms[0] - 2.f * dot, 0.f);
    manc[qrow] = sqrtf(d2);
}

// ---- attn: QK-dist -> p=exp(m-d) -> P*onehot(L) via MFMA.
// 1-D grid, ss = blockIdx & 7 so each XCD keeps ONE 512KB S-chunk L2-resident.
__global__ __launch_bounds__(256, 3) void attn(
    const f16* __restrict__ E, const float* __restrict__ norms,
    const float* __restrict__ manc, const f16* __restrict__ Lcs,
    float* __restrict__ Num)
{
    __shared__ __align__(16) f16 Ss[2][64][136];
    __shared__ __align__(16) f16 Pt[4][16][72];   // per-wave P transpose buffer
    const int tid = threadIdx.x;
    const int w = tid >> 6, lane = tid & 63;
    const int q = lane >> 4, c16 = lane & 15;
    const int ss = blockIdx.x & 7;        // -> XCD via %8 round-robin heuristic
    const int qt = blockIdx.x >> 3;

    f16x8 qf[16];
    const f16* qb = E + (size_t)(N_SUP + qt * 64 + w * 16 + c16) * EMB + q * 8;
#pragma unroll
    for (int ks = 0; ks < 16; ++ks) qf[ks] = *(const f16x8*)(qb + ks * 32);
    float q2[4], mrow[4];
#pragma unroll
    for (int r = 0; r < 4; ++r) {
        q2[r]   = norms[N_SUP + qt * 64 + w * 16 + q * 4 + r];
        mrow[r] = manc[qt * 64 + w * 16 + q * 4 + r];
    }

    f32x4 accPL[4];
#pragma unroll
    for (int nb = 0; nb < 4; ++nb) accPL[nb] = (f32x4){0.f, 0.f, 0.f, 0.f};

    const int sr = tid >> 2, koff0 = (tid & 3) * 8;
    const f16* sbase = E + (size_t)(ss * 512 + sr) * EMB;

    f16x8 g[4];
#pragma unroll
    for (int i = 0; i < 4; ++i) g[i] = *(const f16x8*)(sbase + koff0 + i * 32);
#pragma unroll
    for (int i = 0; i < 4; ++i) *(f16x8*)&Ss[0][sr][koff0 + i * 32] = g[i];
    __syncthreads();

    for (int it = 0; it < 8; ++it) {
        f32x4 accQK[4];
#pragma unroll
        for (int nb = 0; nb < 4; ++nb) accQK[nb] = (f32x4){0.f, 0.f, 0.f, 0.f};
#pragma unroll
        for (int kc = 0; kc < 4; ++kc) {
            const int idx = it * 4 + kc;
            const int cur = idx & 1;
            if (idx + 1 < 32) {
                const int nit = (idx + 1) >> 2, nkc = (idx + 1) & 3;
                const f16* src = sbase + (size_t)(nit * 64) * EMB + nkc * 128 + koff0;
#pragma unroll
                for (int i = 0; i < 4; ++i) g[i] = *(const f16x8*)(src + i * 32);
            }
#pragma unroll
            for (int ksl = 0; ksl < 4; ++ksl) {
#pragma unroll
                for (int nb = 0; nb < 4; ++nb) {
                    f16x8 b = *(const f16x8*)&Ss[cur][nb * 16 + c16][ksl * 32 + q * 8];
                    accQK[nb] = __builtin_amdgcn_mfma_f32_16x16x32_f16(qf[kc * 4 + ksl], b, accQK[nb], 0, 0, 0);
                }
            }
            if (idx + 1 < 32) {
#pragma unroll
                for (int i = 0; i < 4; ++i) *(f16x8*)&Ss[cur ^ 1][sr][koff0 + i * 32] = g[i];
            }
            __syncthreads();
        }
        const int s0g = ss * 512 + it * 64;
#pragma unroll
        for (int nb = 0; nb < 4; ++nb) {
            const int col = s0g + nb * 16 + c16;
            const float s2 = norms[col];
#pragma unroll
            for (int r = 0; r < 4; ++r) {
                float d2 = fmaxf(q2[r] + s2 - 2.f * accQK[nb][r], 0.f);
                float p = __expf(mrow[r] - sqrtf(d2));
                p = fminf(p, 60000.f);     // f16-overflow guard
                Pt[w][q * 4 + r][nb * 16 + c16] = (f16)p;
            }
        }
#pragma unroll
        for (int kc2 = 0; kc2 < 2; ++kc2) {
            f16x8 af = *(const f16x8*)&Pt[w][c16][kc2 * 32 + q * 8];
#pragma unroll
            for (int nbc = 0; nbc < 4; ++nbc) {
                f16x8 bl = *(const f16x8*)(Lcs + (size_t)(nbc * 16 + c16) * N_SUP + s0g + kc2 * 32 + q * 8);
                accPL[nbc] = __builtin_amdgcn_mfma_f32_16x16x32_f16(af, bl, accPL[nbc], 0, 0, 0);
            }
        }
    }
#pragma unroll
    for (int nbc = 0; nbc < 4; ++nbc)
#pragma unroll
        for (int r = 0; r < 4; ++r)
            atomicAdd(&Num[(size_t)(qt * 64 + w * 16 + q * 4 + r) * NCLS + nbc * 16 + c16],
                      accPL[nbc][r]);
}

// ---- finalize: out[q][c] = Num[q][c] / rowsum(Num[q]) ----
__global__ __launch_bounds__(256) void finalize(const float* __restrict__ Num,
                                                float* __restrict__ out) {
    const int tid = threadIdx.x;
    const int w = tid >> 6, lane = tid & 63;
    const int qrow = blockIdx.x * 4 + w;
    float v = Num[(size_t)qrow * NCLS + lane];
    float s = v;
    s += __shfl_xor(s, 1);  s += __shfl_xor(s, 2);  s += __shfl_xor(s, 4);
    s += __shfl_xor(s, 8);  s += __shfl_xor(s, 16); s += __shfl_xor(s, 32);
    out[(size_t)qrow * NCLS + lane] = v / s;
}

extern "C" void kernel_launch(void* const* d_in, const int* in_sizes, int n_in,
                              void* d_out, int out_size, void* d_ws, size_t ws_size,
                              hipStream_t stream) {
    (void)in_sizes; (void)n_in; (void)out_size; (void)ws_size;
    const float* sup  = (const float*)d_in[0];
    const float* qry  = (const float*)d_in[1];
    const float* lab  = (const float*)d_in[2];
    const float* Wenc = (const float*)d_in[3];
    const float* benc = (const float*)d_in[4];
    float* out = (float*)d_out;

    char* ws = (char*)d_ws;
    size_t off = 0;
    f16* Wb = (f16*)(ws + off);        off += (size_t)NCHUNK * 32 * 64 * 8 * 2; // 819200
    f16* E  = (f16*)(ws + off);        off += (size_t)M_TOT * EMB * 2;          // 12582912
    float* norms = (float*)(ws + off); off += (size_t)M_TOT * 4;                // 49152
    int* lbl = (int*)(ws + off);       off += (size_t)N_SUP * 4;                // 16384
    f16* Lcs = (f16*)(ws + off);       off += (size_t)NCLS * N_SUP * 2;         // 524288
    float* manc = (float*)(ws + off);  off += (size_t)N_QRY * 4;                // 32768
    float* Num = (float*)(ws + off);   off += (size_t)N_QRY * NCLS * 4;         // 2097152

    hipMemsetAsync(Num, 0, (size_t)N_QRY * NCLS * 4, stream);

    prep_wb<<<(NCHUNK * 32 * 64 + 255) / 256, 256, 0, stream>>>(Wenc, Wb);
    prep_lbl<<<N_SUP / 256, 256, 0, stream>>>(lab, lbl);
    prep_L<<<NCLS * N_SUP / 256, 256, 0, stream>>>(lbl, Lcs);
    encode<<<M_TOT / 64, 256, 0, stream>>>(sup, qry, Wb, benc, E, norms);
    anchor<<<N_QRY / 256, 256, 0, stream>>>(E, norms, manc);
    attn<<<N_QRY / 64 * 8, 256, 0, stream>>>(E, norms, manc, Lcs, Num);
    finalize<<<N_QRY / 4, 256, 0, stream>>>(Num, out);
}

// Round 8
// 218.430 us; speedup vs baseline: 1.1978x; 1.1707x over previous
//
#include <hip/hip_runtime.h>

#define N_SUP 4096
#define N_QRY 8192
#define IN_DIM 784
#define EMB 512
#define NCLS 64
#define M_TOT (N_SUP + N_QRY)
#define NCHUNK 25   // ceil(784/32)
#define XCH 13      // ceil(784/64)

typedef _Float16 f16;
typedef _Float16 f16x8 __attribute__((ext_vector_type(8)));
typedef float f32x4 __attribute__((ext_vector_type(4)));

// load 8 consecutive fp32 and convert to f16x8
static __device__ __forceinline__ f16x8 cvt8(const float* p) {
    float4 a = *(const float4*)p;
    float4 b = *(const float4*)(p + 4);
    f16x8 v;
    v[0] = (f16)a.x; v[1] = (f16)a.y; v[2] = (f16)a.z; v[3] = (f16)a.w;
    v[4] = (f16)b.x; v[5] = (f16)b.y; v[6] = (f16)b.z; v[7] = (f16)b.w;
    return v;
}

// ---- prep: W (784x512 fp32) -> Wb in MFMA B-frag order ----
__global__ __launch_bounds__(256) void prep_wb(const float* __restrict__ W,
                                               f16* __restrict__ Wb) {
    int g = blockIdx.x * 256 + threadIdx.x;          // 51200 frag-lanes
    if (g >= NCHUNK * 32 * 64) return;
    int chunk = g >> 11;
    int rem = g & 2047;
    int nbg = rem >> 6, lane = rem & 63;
    int n = nbg * 16 + (lane & 15);
    int kbase = chunk * 32 + (lane >> 4) * 8;
    f16x8 v;
#pragma unroll
    for (int j = 0; j < 8; ++j) {
        int k = kbase + j;
        v[j] = (k < IN_DIM) ? (f16)W[(size_t)k * EMB + n] : (f16)0.f;
    }
    *(f16x8*)(Wb + (size_t)g * 8) = v;
}

// ---- prep: one-hot labels -> argmax, wave-per-row (coalesced) ----
__global__ __launch_bounds__(256) void prep_lbl(const float* __restrict__ lab,
                                                int* __restrict__ lbl) {
    const int w = threadIdx.x >> 6, lane = threadIdx.x & 63;
    const int s = blockIdx.x * 4 + w;
    float v = lab[(size_t)s * NCLS + lane];
    int c = lane;
#pragma unroll
    for (int off = 1; off < 64; off <<= 1) {
        float v2 = __shfl_xor(v, off);
        int c2 = __shfl_xor(c, off);
        if (v2 > v || (v2 == v && c2 < c)) { v = v2; c = c2; }
    }
    if (lane == 0) lbl[s] = c;
}

// ---- prep: Lcs[c][s] one-hot transpose (coalesced reads+writes) ----
__global__ __launch_bounds__(256) void prep_L(const int* __restrict__ lbl,
                                              f16* __restrict__ Lcs) {
    int idx = blockIdx.x * 256 + threadIdx.x;
    if (idx >= NCLS * N_SUP) return;
    int c = idx >> 12, s = idx & (N_SUP - 1);
    Lcs[idx] = (lbl[s] == c) ? (f16)1.f : (f16)0.f;
}

// ---- encode: 32 rows x 256 cols per block, grid 768 (3 blocks/CU). ----
__global__ __launch_bounds__(256) void encode(
    const float* __restrict__ sup, const float* __restrict__ qry,
    const f16* __restrict__ Wb, const float* __restrict__ bias,
    f16* __restrict__ E, float* __restrict__ norms)
{
    __shared__ __align__(16) f16 Xs[32][72];
    const int tid = threadIdx.x;
    const int w = tid >> 6, lane = tid & 63;
    const int q = lane >> 4, c16 = lane & 15;
    const int mb = blockIdx.x >> 1;          // row-group 0..383
    const int ch = blockIdx.x & 1;           // col half
    const int m0 = mb * 32;
    const int rbase = (w & 1) * 16;
    const int nbg0 = ch * 16 + (w >> 1) * 8; // global nb offset
    const int cbase = nbg0 * 16;

    f32x4 acc[8];
#pragma unroll
    for (int nb = 0; nb < 8; ++nb) acc[nb] = (f32x4){0.f, 0.f, 0.f, 0.f};

    const int sr = tid >> 3;     // 0..31
    const int sq = tid & 7;      // x8 f16
    const float* xrow;
    {
        int gr = m0 + sr;
        xrow = (gr < N_SUP) ? sup + (size_t)gr * IN_DIM
                            : qry + (size_t)(gr - N_SUP) * IN_DIM;
    }

    f16x8 xg = cvt8(xrow + sq * 8);   // chunk 0, k<64<784 always valid

    for (int c = 0; c < XCH; ++c) {
        __syncthreads();
        *(f16x8*)&Xs[sr][sq * 8] = xg;
        __syncthreads();
        if (c + 1 < XCH) {
            int k = (c + 1) * 64 + sq * 8;
            xg = (k + 8 <= IN_DIM) ? cvt8(xrow + k) : (f16x8){0,0,0,0,0,0,0,0};
        }
#pragma unroll
        for (int kc = 0; kc < 2; ++kc) {
            int c32 = c * 2 + kc;
            if (c32 >= NCHUNK) break;
            f16x8 a = *(const f16x8*)&Xs[rbase + c16][kc * 32 + q * 8];
            const f16* wb = Wb + ((size_t)(c32 * 32 + nbg0) * 64 + lane) * 8;
#pragma unroll
            for (int nb = 0; nb < 8; ++nb) {
                f16x8 b = *(const f16x8*)(wb + (size_t)nb * 512);
                acc[nb] = __builtin_amdgcn_mfma_f32_16x16x32_f16(a, b, acc[nb], 0, 0, 0);
            }
        }
    }

    float nrm[4] = {0.f, 0.f, 0.f, 0.f};
#pragma unroll
    for (int nb = 0; nb < 8; ++nb) {
        int col = cbase + nb * 16 + c16;
        float bv = bias[col];
#pragma unroll
        for (int r = 0; r < 4; ++r) {
            int row = m0 + rbase + q * 4 + r;
            float v = acc[nb][r] + bv;
            E[(size_t)row * EMB + col] = (f16)v;
            nrm[r] += v * v;
        }
    }
#pragma unroll
    for (int r = 0; r < 4; ++r) {
        float v = nrm[r];
        v += __shfl_xor(v, 1); v += __shfl_xor(v, 2);
        v += __shfl_xor(v, 4); v += __shfl_xor(v, 8);
        if (c16 == 0) atomicAdd(&norms[m0 + rbase + q * 4 + r], v);
    }
}

// ---- anchor: m[q] = d(query q, support 0), wave-per-row ----
__global__ __launch_bounds__(256) void anchor(const f16* __restrict__ E,
                                              const float* __restrict__ norms,
                                              float* __restrict__ manc) {
    const int w = threadIdx.x >> 6, lane = threadIdx.x & 63;
    const int qrow = blockIdx.x * 4 + w;
    f16x8 qv = *(const f16x8*)(E + (size_t)(N_SUP + qrow) * EMB + lane * 8);
    f16x8 sv = *(const f16x8*)(E + lane * 8);
    float dot = 0.f;
#pragma unroll
    for (int j = 0; j < 8; ++j) dot += (float)qv[j] * (float)sv[j];
    dot += __shfl_xor(dot, 1);  dot += __shfl_xor(dot, 2);
    dot += __shfl_xor(dot, 4);  dot += __shfl_xor(dot, 8);
    dot += __shfl_xor(dot, 16); dot += __shfl_xor(dot, 32);
    if (lane == 0) {
        float d2 = fmaxf(norms[N_SUP + qrow] + norms[0] - 2.f * dot, 0.f);
        manc[qrow] = sqrtf(d2);
    }
}

// ---- attn: QK-dist -> p=exp(m-d) -> P*onehot(L) via MFMA.
// 1-D grid, ss = blockIdx & 7 (XCD L2 residency). Pads: Ss 144, Pt 80.
__global__ __launch_bounds__(256, 3) void attn(
    const f16* __restrict__ E, const float* __restrict__ norms,
    const float* __restrict__ manc, const f16* __restrict__ Lcs,
    float* __restrict__ Num)
{
    __shared__ __align__(16) f16 Ss[2][64][144];
    __shared__ __align__(16) f16 Pt[4][16][80];   // per-wave P transpose buffer
    const int tid = threadIdx.x;
    const int w = tid >> 6, lane = tid & 63;
    const int q = lane >> 4, c16 = lane & 15;
    const int ss = blockIdx.x & 7;
    const int qt = blockIdx.x >> 3;

    f16x8 qf[16];
    const f16* qb = E + (size_t)(N_SUP + qt * 64 + w * 16 + c16) * EMB + q * 8;
#pragma unroll
    for (int ks = 0; ks < 16; ++ks) qf[ks] = *(const f16x8*)(qb + ks * 32);
    float q2[4], mrow[4];
#pragma unroll
    for (int r = 0; r < 4; ++r) {
        q2[r]   = norms[N_SUP + qt * 64 + w * 16 + q * 4 + r];
        mrow[r] = manc[qt * 64 + w * 16 + q * 4 + r];
    }

    f32x4 accPL[4];
#pragma unroll
    for (int nb = 0; nb < 4; ++nb) accPL[nb] = (f32x4){0.f, 0.f, 0.f, 0.f};

    const int sr = tid >> 2, koff0 = (tid & 3) * 8;
    const f16* sbase = E + (size_t)(ss * 512 + sr) * EMB;

    f16x8 g[4];
#pragma unroll
    for (int i = 0; i < 4; ++i) g[i] = *(const f16x8*)(sbase + koff0 + i * 32);
#pragma unroll
    for (int i = 0; i < 4; ++i) *(f16x8*)&Ss[0][sr][koff0 + i * 32] = g[i];
    __syncthreads();

    for (int it = 0; it < 8; ++it) {
        f32x4 accQK[4];
#pragma unroll
        for (int nb = 0; nb < 4; ++nb) accQK[nb] = (f32x4){0.f, 0.f, 0.f, 0.f};
#pragma unroll
        for (int kc = 0; kc < 4; ++kc) {
            const int idx = it * 4 + kc;
            const int cur = idx & 1;
            if (idx + 1 < 32) {
                const int nit = (idx + 1) >> 2, nkc = (idx + 1) & 3;
                const f16* src = sbase + (size_t)(nit * 64) * EMB + nkc * 128 + koff0;
#pragma unroll
                for (int i = 0; i < 4; ++i) g[i] = *(const f16x8*)(src + i * 32);
            }
#pragma unroll
            for (int ksl = 0; ksl < 4; ++ksl) {
#pragma unroll
                for (int nb = 0; nb < 4; ++nb) {
                    f16x8 b = *(const f16x8*)&Ss[cur][nb * 16 + c16][ksl * 32 + q * 8];
                    accQK[nb] = __builtin_amdgcn_mfma_f32_16x16x32_f16(qf[kc * 4 + ksl], b, accQK[nb], 0, 0, 0);
                }
            }
            if (idx + 1 < 32) {
#pragma unroll
                for (int i = 0; i < 4; ++i) *(f16x8*)&Ss[cur ^ 1][sr][koff0 + i * 32] = g[i];
            }
            __syncthreads();
        }
        const int s0g = ss * 512 + it * 64;
#pragma unroll
        for (int nb = 0; nb < 4; ++nb) {
            const int col = s0g + nb * 16 + c16;
            const float s2 = norms[col];
#pragma unroll
            for (int r = 0; r < 4; ++r) {
                float d2 = fmaxf(q2[r] + s2 - 2.f * accQK[nb][r], 0.f);
                float p = __expf(mrow[r] - sqrtf(d2));
                p = fminf(p, 60000.f);     // f16-overflow guard
                Pt[w][q * 4 + r][nb * 16 + c16] = (f16)p;
            }
        }
#pragma unroll
        for (int kc2 = 0; kc2 < 2; ++kc2) {
            f16x8 af = *(const f16x8*)&Pt[w][c16][kc2 * 32 + q * 8];
#pragma unroll
            for (int nbc = 0; nbc < 4; ++nbc) {
                f16x8 bl = *(const f16x8*)(Lcs + (size_t)(nbc * 16 + c16) * N_SUP + s0g + kc2 * 32 + q * 8);
                accPL[nbc] = __builtin_amdgcn_mfma_f32_16x16x32_f16(af, bl, accPL[nbc], 0, 0, 0);
            }
        }
    }
#pragma unroll
    for (int nbc = 0; nbc < 4; ++nbc)
#pragma unroll
        for (int r = 0; r < 4; ++r)
            atomicAdd(&Num[(size_t)(qt * 64 + w * 16 + q * 4 + r) * NCLS + nbc * 16 + c16],
                      accPL[nbc][r]);
}

// ---- finalize: out[q][c] = Num[q][c] / rowsum(Num[q]) ----
__global__ __launch_bounds__(256) void finalize(const float* __restrict__ Num,
                                                float* __restrict__ out) {
    const int tid = threadIdx.x;
    const int w = tid >> 6, lane = tid & 63;
    const int qrow = blockIdx.x * 4 + w;
    float v = Num[(size_t)qrow * NCLS + lane];
    float s = v;
    s += __shfl_xor(s, 1);  s += __shfl_xor(s, 2);  s += __shfl_xor(s, 4);
    s += __shfl_xor(s, 8);  s += __shfl_xor(s, 16); s += __shfl_xor(s, 32);
    out[(size_t)qrow * NCLS + lane] = v / s;
}

extern "C" void kernel_launch(void* const* d_in, const int* in_sizes, int n_in,
                              void* d_out, int out_size, void* d_ws, size_t ws_size,
                              hipStream_t stream) {
    (void)in_sizes; (void)n_in; (void)out_size; (void)ws_size;
    const float* sup  = (const float*)d_in[0];
    const float* qry  = (const float*)d_in[1];
    const float* lab  = (const float*)d_in[2];
    const float* Wenc = (const float*)d_in[3];
    const float* benc = (const float*)d_in[4];
    float* out = (float*)d_out;

    char* ws = (char*)d_ws;
    size_t off = 0;
    f16* Wb = (f16*)(ws + off);        off += (size_t)NCHUNK * 32 * 64 * 8 * 2; // 819200
    f16* E  = (f16*)(ws + off);        off += (size_t)M_TOT * EMB * 2;          // 12582912
    int* lbl = (int*)(ws + off);       off += (size_t)N_SUP * 4;                // 16384
    f16* Lcs = (f16*)(ws + off);       off += (size_t)NCLS * N_SUP * 2;         // 524288
    float* manc = (float*)(ws + off);  off += (size_t)N_QRY * 4;                // 32768
    float* norms = (float*)(ws + off); off += (size_t)M_TOT * 4;                // 49152
    float* Num = (float*)(ws + off);   off += (size_t)N_QRY * NCLS * 4;         // 2097152

    // norms and Num adjacent: one memset
    hipMemsetAsync(norms, 0, (size_t)M_TOT * 4 + (size_t)N_QRY * NCLS * 4, stream);

    prep_wb<<<(NCHUNK * 32 * 64 + 255) / 256, 256, 0, stream>>>(Wenc, Wb);
    prep_lbl<<<N_SUP / 4, 256, 0, stream>>>(lab, lbl);
    prep_L<<<NCLS * N_SUP / 256, 256, 0, stream>>>(lbl, Lcs);
    encode<<<M_TOT / 32 * 2, 256, 0, stream>>>(sup, qry, Wb, benc, E, norms);
    anchor<<<N_QRY / 4, 256, 0, stream>>>(E, norms, manc);
    attn<<<N_QRY / 64 * 8, 256, 0, stream>>>(E, norms, manc, Lcs, Num);
    finalize<<<N_QRY / 4, 256, 0, stream>>>(Num, out);
}

// Round 9
// 197.830 us; speedup vs baseline: 1.3225x; 1.1041x over previous
//
#include <hip/hip_runtime.h>

#define N_SUP 4096
#define N_QRY 8192
#define IN_DIM 784
#define EMB 512
#define NCLS 64
#define M_TOT (N_SUP + N_QRY)
#define NCHUNK 25   // ceil(784/32)
#define XCH 13      // ceil(784/64)

typedef _Float16 f16;
typedef _Float16 f16x8 __attribute__((ext_vector_type(8)));
typedef float f32x4 __attribute__((ext_vector_type(4)));

// async global->LDS, 16B per lane. LDS dest is wave-uniform base + lane*16.
#define GLDS16(gp, lp)                                                        \
    __builtin_amdgcn_global_load_lds(                                         \
        (const __attribute__((address_space(1))) void*)(gp),                  \
        (__attribute__((address_space(3))) void*)(lp), 16, 0, 0)

// load 8 consecutive fp32 and convert to f16x8
static __device__ __forceinline__ f16x8 cvt8(const float* p) {
    float4 a = *(const float4*)p;
    float4 b = *(const float4*)(p + 4);
    f16x8 v;
    v[0] = (f16)a.x; v[1] = (f16)a.y; v[2] = (f16)a.z; v[3] = (f16)a.w;
    v[4] = (f16)b.x; v[5] = (f16)b.y; v[6] = (f16)b.z; v[7] = (f16)b.w;
    return v;
}

// ---- prep: W (784x512 fp32) -> Wb in MFMA B-frag order ----
__global__ __launch_bounds__(256) void prep_wb(const float* __restrict__ W,
                                               f16* __restrict__ Wb) {
    int g = blockIdx.x * 256 + threadIdx.x;          // 51200 frag-lanes
    if (g >= NCHUNK * 32 * 64) return;
    int chunk = g >> 11;
    int rem = g & 2047;
    int nbg = rem >> 6, lane = rem & 63;
    int n = nbg * 16 + (lane & 15);
    int kbase = chunk * 32 + (lane >> 4) * 8;
    f16x8 v;
#pragma unroll
    for (int j = 0; j < 8; ++j) {
        int k = kbase + j;
        v[j] = (k < IN_DIM) ? (f16)W[(size_t)k * EMB + n] : (f16)0.f;
    }
    *(f16x8*)(Wb + (size_t)g * 8) = v;
}

// ---- prep: one-hot labels -> argmax, wave-per-row (coalesced) ----
__global__ __launch_bounds__(256) void prep_lbl(const float* __restrict__ lab,
                                                int* __restrict__ lbl) {
    const int w = threadIdx.x >> 6, lane = threadIdx.x & 63;
    const int s = blockIdx.x * 4 + w;
    float v = lab[(size_t)s * NCLS + lane];
    int c = lane;
#pragma unroll
    for (int off = 1; off < 64; off <<= 1) {
        float v2 = __shfl_xor(v, off);
        int c2 = __shfl_xor(c, off);
        if (v2 > v || (v2 == v && c2 < c)) { v = v2; c = c2; }
    }
    if (lane == 0) lbl[s] = c;
}

// ---- prep: Lcs[c][s] one-hot transpose (coalesced reads+writes) ----
__global__ __launch_bounds__(256) void prep_L(const int* __restrict__ lbl,
                                              f16* __restrict__ Lcs) {
    int idx = blockIdx.x * 256 + threadIdx.x;
    if (idx >= NCLS * N_SUP) return;
    int c = idx >> 12, s = idx & (N_SUP - 1);
    Lcs[idx] = (lbl[s] == c) ? (f16)1.f : (f16)0.f;
}

// ---- prep: support E rows -> bank-swizzled Sb.
// Sb[s*512 + (lg ^ (s&15))*8 + j] = E[s*512 + lg*8 + j]
// The ds_read pattern in attn applies the same XOR -> uniform 8 dwords/bank.
__global__ __launch_bounds__(256) void prep_sb(const f16* __restrict__ E,
                                               f16* __restrict__ Sb) {
    int g = blockIdx.x * 256 + threadIdx.x;   // 262144 groups of 8 f16
    int s = g >> 6, lg = g & 63;
    f16x8 v = *(const f16x8*)(E + (size_t)s * EMB + lg * 8);
    *(f16x8*)(Sb + (size_t)s * EMB + ((lg ^ (s & 15)) * 8)) = v;
}

// ---- encode: 32 rows x 256 cols per block, grid 768 (3 blocks/CU). ----
__global__ __launch_bounds__(256) void encode(
    const float* __restrict__ sup, const float* __restrict__ qry,
    const f16* __restrict__ Wb, const float* __restrict__ bias,
    f16* __restrict__ E, float* __restrict__ norms)
{
    __shared__ __align__(16) f16 Xs[32][72];
    const int tid = threadIdx.x;
    const int w = tid >> 6, lane = tid & 63;
    const int q = lane >> 4, c16 = lane & 15;
    const int mb = blockIdx.x >> 1;
    const int ch = blockIdx.x & 1;
    const int m0 = mb * 32;
    const int rbase = (w & 1) * 16;
    const int nbg0 = ch * 16 + (w >> 1) * 8;
    const int cbase = nbg0 * 16;

    f32x4 acc[8];
#pragma unroll
    for (int nb = 0; nb < 8; ++nb) acc[nb] = (f32x4){0.f, 0.f, 0.f, 0.f};

    const int sr = tid >> 3;
    const int sq = tid & 7;
    const float* xrow;
    {
        int gr = m0 + sr;
        xrow = (gr < N_SUP) ? sup + (size_t)gr * IN_DIM
                            : qry + (size_t)(gr - N_SUP) * IN_DIM;
    }

    f16x8 xg = cvt8(xrow + sq * 8);

    for (int c = 0; c < XCH; ++c) {
        __syncthreads();
        *(f16x8*)&Xs[sr][sq * 8] = xg;
        __syncthreads();
        if (c + 1 < XCH) {
            int k = (c + 1) * 64 + sq * 8;
            xg = (k + 8 <= IN_DIM) ? cvt8(xrow + k) : (f16x8){0,0,0,0,0,0,0,0};
        }
#pragma unroll
        for (int kc = 0; kc < 2; ++kc) {
            int c32 = c * 2 + kc;
            if (c32 >= NCHUNK) break;
            f16x8 a = *(const f16x8*)&Xs[rbase + c16][kc * 32 + q * 8];
            const f16* wb = Wb + ((size_t)(c32 * 32 + nbg0) * 64 + lane) * 8;
#pragma unroll
            for (int nb = 0; nb < 8; ++nb) {
                f16x8 b = *(const f16x8*)(wb + (size_t)nb * 512);
                acc[nb] = __builtin_amdgcn_mfma_f32_16x16x32_f16(a, b, acc[nb], 0, 0, 0);
            }
        }
    }

    float nrm[4] = {0.f, 0.f, 0.f, 0.f};
#pragma unroll
    for (int nb = 0; nb < 8; ++nb) {
        int col = cbase + nb * 16 + c16;
        float bv = bias[col];
#pragma unroll
        for (int r = 0; r < 4; ++r) {
            int row = m0 + rbase + q * 4 + r;
            float v = acc[nb][r] + bv;
            E[(size_t)row * EMB + col] = (f16)v;
            nrm[r] += v * v;
        }
    }
#pragma unroll
    for (int r = 0; r < 4; ++r) {
        float v = nrm[r];
        v += __shfl_xor(v, 1); v += __shfl_xor(v, 2);
        v += __shfl_xor(v, 4); v += __shfl_xor(v, 8);
        if (c16 == 0) atomicAdd(&norms[m0 + rbase + q * 4 + r], v);
    }
}

// ---- anchor: m[q] = d(query q, support 0), wave-per-row ----
__global__ __launch_bounds__(256) void anchor(const f16* __restrict__ E,
                                              const float* __restrict__ norms,
                                              float* __restrict__ manc) {
    const int w = threadIdx.x >> 6, lane = threadIdx.x & 63;
    const int qrow = blockIdx.x * 4 + w;
    f16x8 qv = *(const f16x8*)(E + (size_t)(N_SUP + qrow) * EMB + lane * 8);
    f16x8 sv = *(const f16x8*)(E + lane * 8);
    float dot = 0.f;
#pragma unroll
    for (int j = 0; j < 8; ++j) dot += (float)qv[j] * (float)sv[j];
    dot += __shfl_xor(dot, 1);  dot += __shfl_xor(dot, 2);
    dot += __shfl_xor(dot, 4);  dot += __shfl_xor(dot, 8);
    dot += __shfl_xor(dot, 16); dot += __shfl_xor(dot, 32);
    if (lane == 0) {
        float d2 = fmaxf(norms[N_SUP + qrow] + norms[0] - 2.f * dot, 0.f);
        manc[qrow] = sqrtf(d2);
    }
}

// ---- attn: 32-support tiles DMA'd into LDS (swizzled, dbuf), 1 barrier/tile.
// QK-dist -> p=exp(m-d) -> Pt round-trip -> P*onehot(L) MFMA.
__global__ __launch_bounds__(256, 2) void attn(
    const f16* __restrict__ E, const float* __restrict__ norms,
    const float* __restrict__ manc, const f16* __restrict__ Lcs,
    const f16* __restrict__ Sb, float* __restrict__ Num)
{
    __shared__ __align__(16) f16 Ss[2][32 * EMB];   // 2 x 32KB
    __shared__ __align__(16) f16 Pt[4][16][40];     // per-wave P transpose
    const int tid = threadIdx.x;
    const int w = tid >> 6, lane = tid & 63;
    const int q = lane >> 4, c16 = lane & 15;
    const int ss = blockIdx.x & 7;        // XCD %8 residency heuristic
    const int qt = blockIdx.x >> 3;

    // resident Q fragments (A-layout m=c16): 64 VGPRs
    f16x8 qf[16];
    const f16* qb = E + (size_t)(N_SUP + qt * 64 + w * 16 + c16) * EMB + q * 8;
#pragma unroll
    for (int ks = 0; ks < 16; ++ks) qf[ks] = *(const f16x8*)(qb + ks * 32);
    float q2[4], mrow[4];
#pragma unroll
    for (int r = 0; r < 4; ++r) {
        q2[r]   = norms[N_SUP + qt * 64 + w * 16 + q * 4 + r];
        mrow[r] = manc[qt * 64 + w * 16 + q * 4 + r];
    }

    f32x4 accPL[4];
#pragma unroll
    for (int nb = 0; nb < 4; ++nb) accPL[nb] = (f32x4){0.f, 0.f, 0.f, 0.f};

    const f16* sb_base = Sb + (size_t)(ss * 512) * EMB;
    const int wslot = w * 512;            // wave's 512-slot region (x16B)

    // prologue: DMA tile 0 -> buf 0
#pragma unroll
    for (int i = 0; i < 8; ++i)
        GLDS16(sb_base + (size_t)(wslot + i * 64 + lane) * 8,
               &Ss[0][(wslot + i * 64) * 8]);
    __syncthreads();

    for (int t = 0; t < 16; ++t) {
        const int cur = t & 1;
        if (t + 1 < 16) {
            const f16* gsrc = sb_base + (size_t)(t + 1) * 32 * EMB;
#pragma unroll
            for (int i = 0; i < 8; ++i)
                GLDS16(gsrc + (size_t)(wslot + i * 64 + lane) * 8,
                       &Ss[cur ^ 1][(wslot + i * 64) * 8]);
        }
        const int s0g = ss * 512 + t * 32;
        // prefetch Lcs B-frags for this tile (L2-hot; latency covered by QK)
        f16x8 bl[4];
#pragma unroll
        for (int nbc = 0; nbc < 4; ++nbc)
            bl[nbc] = *(const f16x8*)(Lcs + (size_t)(nbc * 16 + c16) * N_SUP + s0g + q * 8);

        // QK over full K=512 for 32 supports
        f32x4 accQK[2];
        accQK[0] = (f32x4){0.f, 0.f, 0.f, 0.f};
        accQK[1] = (f32x4){0.f, 0.f, 0.f, 0.f};
#pragma unroll
        for (int kc = 0; kc < 4; ++kc) {
#pragma unroll
            for (int ksl = 0; ksl < 4; ++ksl) {
                const int lg = kc * 16 + ksl * 4 + q;
#pragma unroll
                for (int nb = 0; nb < 2; ++nb) {
                    const int r = nb * 16 + c16;
                    f16x8 b = *(const f16x8*)&Ss[cur][r * EMB + ((lg ^ c16) * 8)];
                    accQK[nb] = __builtin_amdgcn_mfma_f32_16x16x32_f16(
                        qf[kc * 4 + ksl], b, accQK[nb], 0, 0, 0);
                }
            }
        }
        // epilogue: p = exp(m - d) -> Pt (wave-private)
#pragma unroll
        for (int nb = 0; nb < 2; ++nb) {
            const int col = s0g + nb * 16 + c16;
            const float s2 = norms[col];
#pragma unroll
            for (int r = 0; r < 4; ++r) {
                float d2 = fmaxf(q2[r] + s2 - 2.f * accQK[nb][r], 0.f);
                float p = __expf(mrow[r] - sqrtf(d2));
                p = fminf(p, 60000.f);     // f16-overflow guard
                Pt[w][q * 4 + r][nb * 16 + c16] = (f16)p;
            }
        }
        // PV: one K=32 chunk against 4 class-groups
        f16x8 af = *(const f16x8*)&Pt[w][c16][q * 8];
#pragma unroll
        for (int nbc = 0; nbc < 4; ++nbc)
            accPL[nbc] = __builtin_amdgcn_mfma_f32_16x16x32_f16(af, bl[nbc], accPL[nbc], 0, 0, 0);

        __syncthreads();   // drains DMA(t+1) + syncs buffer swap
    }

#pragma unroll
    for (int nbc = 0; nbc < 4; ++nbc)
#pragma unroll
        for (int r = 0; r < 4; ++r)
            atomicAdd(&Num[(size_t)(qt * 64 + w * 16 + q * 4 + r) * NCLS + nbc * 16 + c16],
                      accPL[nbc][r]);
}

// ---- finalize: out[q][c] = Num[q][c] / rowsum(Num[q]) ----
__global__ __launch_bounds__(256) void finalize(const float* __restrict__ Num,
                                                float* __restrict__ out) {
    const int tid = threadIdx.x;
    const int w = tid >> 6, lane = tid & 63;
    const int qrow = blockIdx.x * 4 + w;
    float v = Num[(size_t)qrow * NCLS + lane];
    float s = v;
    s += __shfl_xor(s, 1);  s += __shfl_xor(s, 2);  s += __shfl_xor(s, 4);
    s += __shfl_xor(s, 8);  s += __shfl_xor(s, 16); s += __shfl_xor(s, 32);
    out[(size_t)qrow * NCLS + lane] = v / s;
}

extern "C" void kernel_launch(void* const* d_in, const int* in_sizes, int n_in,
                              void* d_out, int out_size, void* d_ws, size_t ws_size,
                              hipStream_t stream) {
    (void)in_sizes; (void)n_in; (void)out_size; (void)ws_size;
    const float* sup  = (const float*)d_in[0];
    const float* qry  = (const float*)d_in[1];
    const float* lab  = (const float*)d_in[2];
    const float* Wenc = (const float*)d_in[3];
    const float* benc = (const float*)d_in[4];
    float* out = (float*)d_out;

    char* ws = (char*)d_ws;
    size_t off = 0;
    f16* Wb = (f16*)(ws + off);        off += (size_t)NCHUNK * 32 * 64 * 8 * 2; // 819200
    f16* E  = (f16*)(ws + off);        off += (size_t)M_TOT * EMB * 2;          // 12582912
    f16* Sb = (f16*)(ws + off);        off += (size_t)N_SUP * EMB * 2;          // 4194304
    int* lbl = (int*)(ws + off);       off += (size_t)N_SUP * 4;                // 16384
    f16* Lcs = (f16*)(ws + off);       off += (size_t)NCLS * N_SUP * 2;         // 524288
    float* manc = (float*)(ws + off);  off += (size_t)N_QRY * 4;                // 32768
    float* norms = (float*)(ws + off); off += (size_t)M_TOT * 4;                // 49152
    float* Num = (float*)(ws + off);   off += (size_t)N_QRY * NCLS * 4;         // 2097152

    // norms and Num adjacent: one memset
    hipMemsetAsync(norms, 0, (size_t)M_TOT * 4 + (size_t)N_QRY * NCLS * 4, stream);

    prep_wb<<<(NCHUNK * 32 * 64 + 255) / 256, 256, 0, stream>>>(Wenc, Wb);
    prep_lbl<<<N_SUP / 4, 256, 0, stream>>>(lab, lbl);
    prep_L<<<NCLS * N_SUP / 256, 256, 0, stream>>>(lbl, Lcs);
    encode<<<M_TOT / 32 * 2, 256, 0, stream>>>(sup, qry, Wb, benc, E, norms);
    prep_sb<<<N_SUP * 64 / 256, 256, 0, stream>>>(E, Sb);
    anchor<<<N_QRY / 4, 256, 0, stream>>>(E, norms, manc);
    attn<<<N_QRY / 64 * 8, 256, 0, stream>>>(E, norms, manc, Lcs, Sb, Num);
    finalize<<<N_QRY / 4, 256, 0, stream>>>(Num, out);
}